// Round 1
// baseline (3233.442 us; speedup 1.0000x reference)
//
#include <hip/hip_runtime.h>
#include <math.h>

// Llama4TextMoe — fp32 correctness-first baseline.
// Structure:
//   K0 memset counts/offs/cursor
//   K1 router: logits = x@rw, top-1, sigmoid; writes router_scores [E,T] to d_out tail;
//      per-token expert idx + score; atomic counts
//   K2 prefix (1 thread): per-expert slot offsets padded to BM so GEMM tiles never
//      straddle experts
//   K3 scatter: token list[slot]
//   K4 shared up:  sharedH[T,I]   = silu(x@Wg)*(x@Wu)
//   K5 routed up:  routedH[slot,I]= silu((s*x)@Gup_e[:, :I]) * ((s*x)@Gup_e[:, I:])
//   K6 shared down: out[T,H] = sharedH @ Wsd          (plain write)
//   K7 routed down: out[tok,:] += routedH[slot] @ Dp_e (guarded RMW; top-1 => race-free,
//      stream order after K6)

#define BM 64
#define BN 64
#define BK 16
#define PAD 68   // BM+4: breaks power-of-2 bank stride, keeps float4 alignment (68%4==0)

__global__ __launch_bounds__(256) void router_kernel(
    const float* __restrict__ x, const float* __restrict__ rw,
    float* __restrict__ scores_out, int* __restrict__ eidx,
    float* __restrict__ score, int* __restrict__ counts, int T, int H, int E)
{
    int g = blockIdx.x * 256 + threadIdx.x;
    int t = g >> 3, e = g & 7;          // assumes E == 8
    if (t >= T) return;
    const float* xr = x + (size_t)t * H;
    float acc = 0.f;
    for (int k = 0; k < H; k++) acc = fmaf(xr[k], rw[k * E + e], acc);
    // top-1 across the 8 lanes of this token (ties -> lowest index, jax.lax.top_k)
    float bv = acc; int bi = e;
    #pragma unroll
    for (int off = 4; off; off >>= 1) {
        float ov = __shfl_xor(bv, off, 8);
        int   oi = __shfl_xor(bi, off, 8);
        if (ov > bv || (ov == bv && oi < bi)) { bv = ov; bi = oi; }
    }
    float sig = 1.f / (1.f + __expf(-bv));
    scores_out[(size_t)e * T + t] = (e == bi) ? sig : 0.f;   // sigmoid(-inf)==0
    if (e == 0) {
        eidx[t] = bi;
        score[t] = sig;
        atomicAdd(&counts[bi], 1);
    }
}

__global__ void prefix_kernel(const int* __restrict__ counts, int* __restrict__ offs, int E)
{
    if (blockIdx.x == 0 && threadIdx.x == 0) {
        int run = 0;
        for (int e = 0; e < E; e++) {
            offs[e] = run;
            run += ((counts[e] + BM - 1) / BM) * BM;   // pad so tiles never straddle experts
        }
    }
}

__global__ __launch_bounds__(256) void scatter_kernel(
    const int* __restrict__ eidx, const int* __restrict__ offs,
    int* __restrict__ cursor, int* __restrict__ list, int T)
{
    int t = blockIdx.x * 256 + threadIdx.x;
    if (t >= T) return;
    int e = eidx[t];
    int pos = offs[e] + atomicAdd(&cursor[e], 1);
    list[pos] = t;
}

// ---- shared expert, gate+up with fused SwiGLU: Hout[T,I] ----
__global__ __launch_bounds__(256) void shared_up_gemm(
    const float* __restrict__ X, const float* __restrict__ Wg,
    const float* __restrict__ Wu, float* __restrict__ Hout, int H, int I)
{
    __shared__ float As[BK][PAD];
    __shared__ float Bg[BK][PAD];
    __shared__ float Bu[BK][PAD];
    int tid = threadIdx.x;
    int tx = tid & 15, ty = tid >> 4;
    int m0 = blockIdx.y * BM, n0 = blockIdx.x * BN;
    int lrow = tid >> 2, lk4 = (tid & 3) * 4;
    int lkr  = tid >> 4, lc4 = (tid & 15) * 4;
    float accg[4][4] = {{0.f}}, accu[4][4] = {{0.f}};
    const float* Ap  = X  + (size_t)(m0 + lrow) * H + lk4;
    const float* Bgp = Wg + (size_t)lkr * I + n0 + lc4;
    const float* Bup = Wu + (size_t)lkr * I + n0 + lc4;
    for (int k0 = 0; k0 < H; k0 += BK) {
        float4 av = *(const float4*)(Ap  + k0);
        float4 gv = *(const float4*)(Bgp + (size_t)k0 * I);
        float4 uv = *(const float4*)(Bup + (size_t)k0 * I);
        __syncthreads();
        As[lk4 + 0][lrow] = av.x; As[lk4 + 1][lrow] = av.y;
        As[lk4 + 2][lrow] = av.z; As[lk4 + 3][lrow] = av.w;
        *(float4*)&Bg[lkr][lc4] = gv;
        *(float4*)&Bu[lkr][lc4] = uv;
        __syncthreads();
        #pragma unroll
        for (int kk = 0; kk < BK; kk++) {
            float4 a4 = *(const float4*)&As[kk][ty * 4];
            float4 g4 = *(const float4*)&Bg[kk][tx * 4];
            float4 u4 = *(const float4*)&Bu[kk][tx * 4];
            float aa[4] = {a4.x, a4.y, a4.z, a4.w};
            float gg[4] = {g4.x, g4.y, g4.z, g4.w};
            float uu[4] = {u4.x, u4.y, u4.z, u4.w};
            #pragma unroll
            for (int i = 0; i < 4; i++)
                #pragma unroll
                for (int j = 0; j < 4; j++) {
                    accg[i][j] = fmaf(aa[i], gg[j], accg[i][j]);
                    accu[i][j] = fmaf(aa[i], uu[j], accu[i][j]);
                }
        }
    }
    #pragma unroll
    for (int i = 0; i < 4; i++) {
        float r[4];
        #pragma unroll
        for (int j = 0; j < 4; j++) {
            float g = accg[i][j], u = accu[i][j];
            r[j] = u * (g / (1.f + __expf(-g)));
        }
        float4 o; o.x = r[0]; o.y = r[1]; o.z = r[2]; o.w = r[3];
        *(float4*)(Hout + (size_t)(m0 + ty * 4 + i) * I + n0 + tx * 4) = o;
    }
}

// ---- routed experts, gate+up with fused SwiGLU, gathered+scaled A ----
__global__ __launch_bounds__(256) void routed_up_gemm(
    const float* __restrict__ X, const float* __restrict__ GUP,
    const int* __restrict__ counts, const int* __restrict__ offs,
    const int* __restrict__ list, const float* __restrict__ score,
    float* __restrict__ Hout, int H, int I)
{
    int e = blockIdx.z;
    int count = counts[e];
    int mbase = blockIdx.y * BM;
    if (mbase >= count) return;           // uniform early-exit (before any sync)
    const float* W = GUP + (size_t)e * H * 2 * I;
    __shared__ float As[BK][PAD];
    __shared__ float Bg[BK][PAD];
    __shared__ float Bu[BK][PAD];
    int tid = threadIdx.x;
    int tx = tid & 15, ty = tid >> 4;
    int n0 = blockIdx.x * BN;
    int lrow = tid >> 2, lk4 = (tid & 3) * 4;
    int lkr  = tid >> 4, lc4 = (tid & 15) * 4;
    int off_e = offs[e];
    int jrow = mbase + lrow;
    bool valid = jrow < count;
    int tok = valid ? list[off_e + jrow] : 0;
    float s = valid ? score[tok] : 0.f;   // invalid rows -> zeros in LDS -> zero output rows
    float accg[4][4] = {{0.f}}, accu[4][4] = {{0.f}};
    const float* Ap  = X + (size_t)tok * H + lk4;
    const float* Bgp = W + (size_t)lkr * (2 * I) + n0 + lc4;
    const float* Bup = Bgp + I;
    for (int k0 = 0; k0 < H; k0 += BK) {
        float4 av = *(const float4*)(Ap  + k0);
        float4 gv = *(const float4*)(Bgp + (size_t)k0 * (2 * I));
        float4 uv = *(const float4*)(Bup + (size_t)k0 * (2 * I));
        __syncthreads();
        As[lk4 + 0][lrow] = av.x * s; As[lk4 + 1][lrow] = av.y * s;
        As[lk4 + 2][lrow] = av.z * s; As[lk4 + 3][lrow] = av.w * s;
        *(float4*)&Bg[lkr][lc4] = gv;
        *(float4*)&Bu[lkr][lc4] = uv;
        __syncthreads();
        #pragma unroll
        for (int kk = 0; kk < BK; kk++) {
            float4 a4 = *(const float4*)&As[kk][ty * 4];
            float4 g4 = *(const float4*)&Bg[kk][tx * 4];
            float4 u4 = *(const float4*)&Bu[kk][tx * 4];
            float aa[4] = {a4.x, a4.y, a4.z, a4.w};
            float gg[4] = {g4.x, g4.y, g4.z, g4.w};
            float uu[4] = {u4.x, u4.y, u4.z, u4.w};
            #pragma unroll
            for (int i = 0; i < 4; i++)
                #pragma unroll
                for (int j = 0; j < 4; j++) {
                    accg[i][j] = fmaf(aa[i], gg[j], accg[i][j]);
                    accu[i][j] = fmaf(aa[i], uu[j], accu[i][j]);
                }
        }
    }
    #pragma unroll
    for (int i = 0; i < 4; i++) {
        float r[4];
        #pragma unroll
        for (int j = 0; j < 4; j++) {
            float g = accg[i][j], u = accu[i][j];
            r[j] = u * (g / (1.f + __expf(-g)));
        }
        float4 o; o.x = r[0]; o.y = r[1]; o.z = r[2]; o.w = r[3];
        *(float4*)(Hout + (size_t)(off_e + mbase + ty * 4 + i) * I + n0 + tx * 4) = o;
    }
}

// ---- shared down: out[T,H] = A[T,I] @ W[I,H] (plain write) ----
__global__ __launch_bounds__(256) void shared_down_gemm(
    const float* __restrict__ A, const float* __restrict__ W,
    float* __restrict__ out, int I, int H)
{
    __shared__ float As[BK][PAD];
    __shared__ float Bs[BK][PAD];
    int tid = threadIdx.x;
    int tx = tid & 15, ty = tid >> 4;
    int m0 = blockIdx.y * BM, n0 = blockIdx.x * BN;
    int lrow = tid >> 2, lk4 = (tid & 3) * 4;
    int lkr  = tid >> 4, lc4 = (tid & 15) * 4;
    float acc[4][4] = {{0.f}};
    const float* Ap = A + (size_t)(m0 + lrow) * I + lk4;
    const float* Bp = W + (size_t)lkr * H + n0 + lc4;
    for (int k0 = 0; k0 < I; k0 += BK) {
        float4 av = *(const float4*)(Ap + k0);
        float4 bv = *(const float4*)(Bp + (size_t)k0 * H);
        __syncthreads();
        As[lk4 + 0][lrow] = av.x; As[lk4 + 1][lrow] = av.y;
        As[lk4 + 2][lrow] = av.z; As[lk4 + 3][lrow] = av.w;
        *(float4*)&Bs[lkr][lc4] = bv;
        __syncthreads();
        #pragma unroll
        for (int kk = 0; kk < BK; kk++) {
            float4 a4 = *(const float4*)&As[kk][ty * 4];
            float4 b4 = *(const float4*)&Bs[kk][tx * 4];
            float aa[4] = {a4.x, a4.y, a4.z, a4.w};
            float bb[4] = {b4.x, b4.y, b4.z, b4.w};
            #pragma unroll
            for (int i = 0; i < 4; i++)
                #pragma unroll
                for (int j = 0; j < 4; j++)
                    acc[i][j] = fmaf(aa[i], bb[j], acc[i][j]);
        }
    }
    #pragma unroll
    for (int i = 0; i < 4; i++) {
        float4 o; o.x = acc[i][0]; o.y = acc[i][1]; o.z = acc[i][2]; o.w = acc[i][3];
        *(float4*)(out + (size_t)(m0 + ty * 4 + i) * H + n0 + tx * 4) = o;
    }
}

// ---- routed down: out[tok,:] += Hin[slot,:] @ Dp_e (guarded RMW scatter) ----
__global__ __launch_bounds__(256) void routed_down_gemm(
    const float* __restrict__ Hin, const float* __restrict__ DP,
    const int* __restrict__ counts, const int* __restrict__ offs,
    const int* __restrict__ list, float* __restrict__ out, int I, int H)
{
    int e = blockIdx.z;
    int count = counts[e];
    int mbase = blockIdx.y * BM;
    if (mbase >= count) return;
    const float* W = DP + (size_t)e * I * H;
    __shared__ float As[BK][PAD];
    __shared__ float Bs[BK][PAD];
    int tid = threadIdx.x;
    int tx = tid & 15, ty = tid >> 4;
    int n0 = blockIdx.x * BN;
    int lrow = tid >> 2, lk4 = (tid & 3) * 4;
    int lkr  = tid >> 4, lc4 = (tid & 15) * 4;
    int off_e = offs[e];
    float acc[4][4] = {{0.f}};
    const float* Ap = Hin + (size_t)(off_e + mbase + lrow) * I + lk4;
    const float* Bp = W + (size_t)lkr * H + n0 + lc4;
    for (int k0 = 0; k0 < I; k0 += BK) {
        float4 av = *(const float4*)(Ap + k0);
        float4 bv = *(const float4*)(Bp + (size_t)k0 * H);
        __syncthreads();
        As[lk4 + 0][lrow] = av.x; As[lk4 + 1][lrow] = av.y;
        As[lk4 + 2][lrow] = av.z; As[lk4 + 3][lrow] = av.w;
        *(float4*)&Bs[lkr][lc4] = bv;
        __syncthreads();
        #pragma unroll
        for (int kk = 0; kk < BK; kk++) {
            float4 a4 = *(const float4*)&As[kk][ty * 4];
            float4 b4 = *(const float4*)&Bs[kk][tx * 4];
            float aa[4] = {a4.x, a4.y, a4.z, a4.w};
            float bb[4] = {b4.x, b4.y, b4.z, b4.w};
            #pragma unroll
            for (int i = 0; i < 4; i++)
                #pragma unroll
                for (int j = 0; j < 4; j++)
                    acc[i][j] = fmaf(aa[i], bb[j], acc[i][j]);
        }
    }
    #pragma unroll
    for (int i = 0; i < 4; i++) {
        int row_j = mbase + ty * 4 + i;
        if (row_j < count) {
            int tok = list[off_e + row_j];
            float* op = out + (size_t)tok * H + n0 + tx * 4;
            float4 o = *(float4*)op;
            o.x += acc[i][0]; o.y += acc[i][1]; o.z += acc[i][2]; o.w += acc[i][3];
            *(float4*)op = o;
        }
    }
}

extern "C" void kernel_launch(void* const* d_in, const int* in_sizes, int n_in,
                              void* d_out, int out_size, void* d_ws, size_t ws_size,
                              hipStream_t stream)
{
    const float* x   = (const float*)d_in[0];
    const float* rw  = (const float*)d_in[1];
    const float* gup = (const float*)d_in[2];
    const float* dp  = (const float*)d_in[3];
    const float* sg  = (const float*)d_in[4];
    const float* su  = (const float*)d_in[5];
    const float* sd  = (const float*)d_in[6];

    const int H = 2048, I = 4096, E = 8;
    const int T = in_sizes[0] / H;   // 2048

    float* out        = (float*)d_out;
    float* scores_out = out + (size_t)T * H;   // router_scores [E,T]

    const int slotsCap = T + E * BM;           // padded per-expert regions
    char*  ws      = (char*)d_ws;
    float* routedH = (float*)ws;                                   // [slotsCap, I]
    float* sharedH = routedH + (size_t)slotsCap * I;               // [T, I]
    int*   list    = (int*)(sharedH + (size_t)T * I);              // [slotsCap]
    int*   eidx    = list + slotsCap;                              // [T]
    float* score   = (float*)(eidx + T);                           // [T]
    int*   counts  = (int*)(score + T);                            // [E]
    int*   offs    = counts + E;                                   // [E]
    int*   cursor  = offs + E;                                     // [E]

    hipMemsetAsync(counts, 0, 3 * E * sizeof(int), stream);
    router_kernel<<<(T * E) / 256, 256, 0, stream>>>(x, rw, scores_out, eidx, score, counts, T, H, E);
    prefix_kernel<<<1, 1, 0, stream>>>(counts, offs, E);
    scatter_kernel<<<(T + 255) / 256, 256, 0, stream>>>(eidx, offs, cursor, list, T);
    shared_up_gemm<<<dim3(I / BN, T / BM), 256, 0, stream>>>(x, sg, su, sharedH, H, I);
    routed_up_gemm<<<dim3(I / BN, T / BM, E), 256, 0, stream>>>(x, gup, counts, offs, list, score, routedH, H, I);
    shared_down_gemm<<<dim3(H / BN, T / BM), 256, 0, stream>>>(sharedH, sd, out, I, H);
    routed_down_gemm<<<dim3(H / BN, T / BM, E), 256, 0, stream>>>(routedH, dp, counts, offs, list, out, I, H);
}

// Round 2
// 846.369 us; speedup vs baseline: 3.8204x; 3.8204x over previous
//
#include <hip/hip_runtime.h>
#include <math.h>

// Llama4TextMoe — bf16 MFMA version.
//   router (fp32, exact)  -> scores, top-1 idx
//   prefix (1 thread)     -> per-expert padded offsets + flat tile list (e, mbase)
//   scatter               -> slot -> token list
//   shared_up  [T,H]x[H,I]x2 -> SwiGLU -> sharedH bf16 [T,I]
//   routed_up  gathered+scaled rows -> SwiGLU -> routedH bf16 [slots,I]
//   fused_down out[tok,:] = sharedH[tok]@Wsd + routedH[slot]@Dp_e  (plain write,
//              every token appears in exactly one slot since TOP_K=1)
// GEMM core: 128x128 tile, BK=32, 4 waves (2x2), mfma_f32_16x16x32_bf16,
// fp32->bf16 conversion fused into LDS staging (v_cvt_pk via __bf16 casts).

#define BM 128
#define BN 128
#define BK 32
#define LDP 56        // LDS row pitch in bf16 elems: 112B rows -> 16B-aligned b128, 2-way banks
#define MAXT 32

typedef float f32x4 __attribute__((ext_vector_type(4)));
typedef short bf16x8 __attribute__((ext_vector_type(8)));
typedef __bf16 bf2 __attribute__((ext_vector_type(2)));

__device__ inline unsigned int pk2(float a, float b) {
    union { bf2 h; unsigned int u; } c;
    c.h[0] = (__bf16)a; c.h[1] = (__bf16)b;   // compiler fuses to v_cvt_pk_bf16_f32
    return c.u;
}
__device__ inline unsigned short f2bf(float a) {
    union { __bf16 h; unsigned short u; } c; c.h = (__bf16)a; return c.u;
}
__device__ inline void lds_st8(short* dst, float a, float b, float c, float d) {
    unsigned long long v = (unsigned long long)pk2(a, b) |
                           ((unsigned long long)pk2(c, d) << 32);
    *(unsigned long long*)dst = v;   // 8B store, dst is 8B-aligned
}

// ---------------- router / bookkeeping ----------------

__global__ __launch_bounds__(256) void router_kernel(
    const float* __restrict__ x, const float* __restrict__ rw,
    float* __restrict__ scores_out, int* __restrict__ eidx,
    float* __restrict__ score, int* __restrict__ counts, int T, int H, int E)
{
    int g = blockIdx.x * 256 + threadIdx.x;
    int t = g >> 3, e = g & 7;          // E == 8
    if (t >= T) return;
    const float* xr = x + (size_t)t * H;
    float acc = 0.f;
    for (int k = 0; k < H; k++) acc = fmaf(xr[k], rw[k * E + e], acc);
    float bv = acc; int bi = e;
    #pragma unroll
    for (int off = 4; off; off >>= 1) {
        float ov = __shfl_xor(bv, off, 8);
        int   oi = __shfl_xor(bi, off, 8);
        if (ov > bv || (ov == bv && oi < bi)) { bv = ov; bi = oi; }
    }
    float sig = 1.f / (1.f + __expf(-bv));
    scores_out[(size_t)e * T + t] = (e == bi) ? sig : 0.f;
    if (e == 0) {
        eidx[t] = bi;
        score[t] = sig;
        atomicAdd(&counts[bi], 1);
    }
}

__global__ void prefix_kernel(const int* __restrict__ counts, int* __restrict__ offs,
                              int* __restrict__ tile_e, int* __restrict__ tile_m,
                              int* __restrict__ ntile, int E)
{
    if (blockIdx.x == 0 && threadIdx.x == 0) {
        int run = 0, nt = 0;
        for (int e = 0; e < E; e++) {
            offs[e] = run;
            int c = counts[e];
            int t = (c + BM - 1) / BM;
            for (int i = 0; i < t; i++) { tile_e[nt] = e; tile_m[nt] = i * BM; nt++; }
            run += t * BM;
        }
        ntile[0] = nt;
    }
}

__global__ __launch_bounds__(256) void scatter_kernel(
    const int* __restrict__ eidx, const int* __restrict__ offs,
    int* __restrict__ cursor, int* __restrict__ list, int T)
{
    int t = blockIdx.x * 256 + threadIdx.x;
    if (t >= T) return;
    int e = eidx[t];
    int pos = offs[e] + atomicAdd(&cursor[e], 1);
    list[pos] = t;
}

// ---------------- shared expert up (gate+up, fused SwiGLU) ----------------

__global__ __launch_bounds__(256, 2) void shared_up(
    const float* __restrict__ X, const float* __restrict__ Wg,
    const float* __restrict__ Wu, unsigned short* __restrict__ Hout,
    int H, int I)
{
    __shared__ short As[BM][LDP], Bg[BN][LDP], Bu[BN][LDP];
    const int tid = threadIdx.x;
    const int lane = tid & 63, wid = tid >> 6;
    const int wr = wid >> 1, wc = wid & 1;
    const int m0 = blockIdx.y * BM, n0 = blockIdx.x * BN;

    int arow[4], ac4[4], bn_[4], bk4[4];
    const float *ap[4], *bgp[4], *bup[4];
#pragma unroll
    for (int p = 0; p < 4; p++) {
        int idx = tid + p * 256;
        arow[p] = idx >> 3; ac4[p] = (idx & 7) * 4;
        ap[p] = X + (size_t)(m0 + arow[p]) * H + ac4[p];
        bn_[p] = idx & 127; bk4[p] = (idx >> 7) * 4;
        bgp[p] = Wg + (size_t)bk4[p] * I + (n0 + bn_[p]);
        bup[p] = Wu + (size_t)bk4[p] * I + (n0 + bn_[p]);
    }

    f32x4 accg[4][4], accu[4][4];
#pragma unroll
    for (int i = 0; i < 4; i++)
#pragma unroll
        for (int j = 0; j < 4; j++) {
            accg[i][j] = (f32x4){0.f, 0.f, 0.f, 0.f};
            accu[i][j] = (f32x4){0.f, 0.f, 0.f, 0.f};
        }

    float4 va[4], vg[4], vu[4];
#pragma unroll
    for (int p = 0; p < 4; p++) {
        va[p] = *(const float4*)ap[p];
        const float* g = bgp[p]; const float* u = bup[p];
        vg[p] = make_float4(g[0], g[(size_t)I], g[2*(size_t)I], g[3*(size_t)I]);
        vu[p] = make_float4(u[0], u[(size_t)I], u[2*(size_t)I], u[3*(size_t)I]);
    }

    const int nK = H / BK;
    const int kh = (lane >> 4) * 8;
    for (int kt = 0; kt < nK; kt++) {
        __syncthreads();
#pragma unroll
        for (int p = 0; p < 4; p++) {
            lds_st8(&As[arow[p]][ac4[p]], va[p].x, va[p].y, va[p].z, va[p].w);
            lds_st8(&Bg[bn_[p]][bk4[p]], vg[p].x, vg[p].y, vg[p].z, vg[p].w);
            lds_st8(&Bu[bn_[p]][bk4[p]], vu[p].x, vu[p].y, vu[p].z, vu[p].w);
        }
        __syncthreads();
        if (kt + 1 < nK) {
            const int k0 = (kt + 1) * BK;
#pragma unroll
            for (int p = 0; p < 4; p++) {
                va[p] = *(const float4*)(ap[p] + k0);
                const float* g = bgp[p] + (size_t)k0 * I;
                const float* u = bup[p] + (size_t)k0 * I;
                vg[p] = make_float4(g[0], g[(size_t)I], g[2*(size_t)I], g[3*(size_t)I]);
                vu[p] = make_float4(u[0], u[(size_t)I], u[2*(size_t)I], u[3*(size_t)I]);
            }
        }
        bf16x8 af[4], gf[4], uf[4];
#pragma unroll
        for (int q = 0; q < 4; q++) {
            af[q] = *(const bf16x8*)&As[wr*64 + q*16 + (lane & 15)][kh];
            gf[q] = *(const bf16x8*)&Bg[wc*64 + q*16 + (lane & 15)][kh];
            uf[q] = *(const bf16x8*)&Bu[wc*64 + q*16 + (lane & 15)][kh];
        }
#pragma unroll
        for (int mi = 0; mi < 4; mi++)
#pragma unroll
            for (int nj = 0; nj < 4; nj++) {
                accg[mi][nj] = __builtin_amdgcn_mfma_f32_16x16x32_bf16(af[mi], gf[nj], accg[mi][nj], 0, 0, 0);
                accu[mi][nj] = __builtin_amdgcn_mfma_f32_16x16x32_bf16(af[mi], uf[nj], accu[mi][nj], 0, 0, 0);
            }
    }

    const int rb = (lane >> 4) * 4, cb = lane & 15;
#pragma unroll
    for (int mi = 0; mi < 4; mi++)
#pragma unroll
        for (int nj = 0; nj < 4; nj++) {
            int col = n0 + wc*64 + nj*16 + cb;
#pragma unroll
            for (int j = 0; j < 4; j++) {
                float g = accg[mi][nj][j], u = accu[mi][nj][j];
                float r = u * g * __builtin_amdgcn_rcpf(1.f + __expf(-g));
                int row = m0 + wr*64 + mi*16 + rb + j;
                Hout[(size_t)row * I + col] = f2bf(r);
            }
        }
}

// ---------------- routed experts up (gathered + score-scaled A) ----------------

__global__ __launch_bounds__(256, 2) void routed_up(
    const float* __restrict__ X, const float* __restrict__ GUP,
    const int* __restrict__ counts, const int* __restrict__ offs,
    const int* __restrict__ list, const float* __restrict__ score,
    const int* __restrict__ tile_e, const int* __restrict__ tile_m,
    const int* __restrict__ ntile,
    unsigned short* __restrict__ Hout, int H, int I)
{
    const int gt = blockIdx.y;
    if (gt >= ntile[0]) return;
    const int e = tile_e[gt], mbase = tile_m[gt];
    const int count = counts[e], off_e = offs[e];
    const float* W = GUP + (size_t)e * H * (2 * I);
    const size_t ldw = 2 * (size_t)I;

    __shared__ short As[BM][LDP], Bg[BN][LDP], Bu[BN][LDP];
    const int tid = threadIdx.x;
    const int lane = tid & 63, wid = tid >> 6;
    const int wr = wid >> 1, wc = wid & 1;
    const int n0 = blockIdx.x * BN;

    int arow[4], ac4[4], bn_[4], bk4[4];
    const float *ap[4], *bgp[4], *bup[4];
    float sv[4];
#pragma unroll
    for (int p = 0; p < 4; p++) {
        int idx = tid + p * 256;
        arow[p] = idx >> 3; ac4[p] = (idx & 7) * 4;
        int gr = mbase + arow[p];
        int tok = 0; float s = 0.f;
        if (gr < count) { tok = list[off_e + gr]; s = score[tok]; }
        sv[p] = s;
        ap[p] = X + (size_t)tok * H + ac4[p];
        bn_[p] = idx & 127; bk4[p] = (idx >> 7) * 4;
        bgp[p] = W + (size_t)bk4[p] * ldw + (n0 + bn_[p]);
        bup[p] = bgp[p] + I;
    }

    f32x4 accg[4][4], accu[4][4];
#pragma unroll
    for (int i = 0; i < 4; i++)
#pragma unroll
        for (int j = 0; j < 4; j++) {
            accg[i][j] = (f32x4){0.f, 0.f, 0.f, 0.f};
            accu[i][j] = (f32x4){0.f, 0.f, 0.f, 0.f};
        }

    float4 va[4], vg[4], vu[4];
#pragma unroll
    for (int p = 0; p < 4; p++) {
        va[p] = *(const float4*)ap[p];
        const float* g = bgp[p]; const float* u = bup[p];
        vg[p] = make_float4(g[0], g[ldw], g[2*ldw], g[3*ldw]);
        vu[p] = make_float4(u[0], u[ldw], u[2*ldw], u[3*ldw]);
    }

    const int nK = H / BK;
    const int kh = (lane >> 4) * 8;
    for (int kt = 0; kt < nK; kt++) {
        __syncthreads();
#pragma unroll
        for (int p = 0; p < 4; p++) {
            float s = sv[p];
            lds_st8(&As[arow[p]][ac4[p]], va[p].x * s, va[p].y * s, va[p].z * s, va[p].w * s);
            lds_st8(&Bg[bn_[p]][bk4[p]], vg[p].x, vg[p].y, vg[p].z, vg[p].w);
            lds_st8(&Bu[bn_[p]][bk4[p]], vu[p].x, vu[p].y, vu[p].z, vu[p].w);
        }
        __syncthreads();
        if (kt + 1 < nK) {
            const int k0 = (kt + 1) * BK;
#pragma unroll
            for (int p = 0; p < 4; p++) {
                va[p] = *(const float4*)(ap[p] + k0);
                const float* g = bgp[p] + (size_t)k0 * ldw;
                const float* u = bup[p] + (size_t)k0 * ldw;
                vg[p] = make_float4(g[0], g[ldw], g[2*ldw], g[3*ldw]);
                vu[p] = make_float4(u[0], u[ldw], u[2*ldw], u[3*ldw]);
            }
        }
        bf16x8 af[4], gf[4], uf[4];
#pragma unroll
        for (int q = 0; q < 4; q++) {
            af[q] = *(const bf16x8*)&As[wr*64 + q*16 + (lane & 15)][kh];
            gf[q] = *(const bf16x8*)&Bg[wc*64 + q*16 + (lane & 15)][kh];
            uf[q] = *(const bf16x8*)&Bu[wc*64 + q*16 + (lane & 15)][kh];
        }
#pragma unroll
        for (int mi = 0; mi < 4; mi++)
#pragma unroll
            for (int nj = 0; nj < 4; nj++) {
                accg[mi][nj] = __builtin_amdgcn_mfma_f32_16x16x32_bf16(af[mi], gf[nj], accg[mi][nj], 0, 0, 0);
                accu[mi][nj] = __builtin_amdgcn_mfma_f32_16x16x32_bf16(af[mi], uf[nj], accu[mi][nj], 0, 0, 0);
            }
    }

    const int rb = (lane >> 4) * 4, cb = lane & 15;
#pragma unroll
    for (int mi = 0; mi < 4; mi++)
#pragma unroll
        for (int nj = 0; nj < 4; nj++) {
            int col = n0 + wc*64 + nj*16 + cb;
#pragma unroll
            for (int j = 0; j < 4; j++) {
                float g = accg[mi][nj][j], u = accu[mi][nj][j];
                float r = u * g * __builtin_amdgcn_rcpf(1.f + __expf(-g));
                int row = off_e + mbase + wr*64 + mi*16 + rb + j;
                Hout[(size_t)row * I + col] = f2bf(r);
            }
        }
}

// ---------------- fused down: out[tok] = SH[tok]@Wsd + RH[slot]@Dp_e ----------------

__global__ __launch_bounds__(256, 2) void fused_down(
    const unsigned short* __restrict__ SH, const unsigned short* __restrict__ RH,
    const float* __restrict__ Wsd, const float* __restrict__ DP,
    const int* __restrict__ counts, const int* __restrict__ offs,
    const int* __restrict__ list,
    const int* __restrict__ tile_e, const int* __restrict__ tile_m,
    const int* __restrict__ ntile,
    float* __restrict__ out, int I, int H)
{
    const int gt = blockIdx.y;
    if (gt >= ntile[0]) return;
    const int e = tile_e[gt], mbase = tile_m[gt];
    const int count = counts[e], off_e = offs[e];
    const float* W2 = DP + (size_t)e * I * H;

    __shared__ short A1[BM][LDP], A2[BM][LDP], B1[BN][LDP], B2[BN][LDP];
    __shared__ int toks[BM];
    const int tid = threadIdx.x;
    const int lane = tid & 63, wid = tid >> 6;
    const int wr = wid >> 1, wc = wid & 1;
    const int n0 = blockIdx.x * BN;

    if (tid < BM) {
        int gr = mbase + tid;
        toks[tid] = (gr < count) ? list[off_e + gr] : -1;
    }
    __syncthreads();

    int a_row[2], a_c8[2];
    const unsigned short *a1p[2], *a2p[2];
#pragma unroll
    for (int p = 0; p < 2; p++) {
        int idx = tid + p * 256;
        a_row[p] = idx >> 2; a_c8[p] = (idx & 3) * 8;
        int tok = toks[a_row[p]]; if (tok < 0) tok = 0;
        a1p[p] = SH + (size_t)tok * I + a_c8[p];
        a2p[p] = RH + (size_t)(off_e + mbase + a_row[p]) * I + a_c8[p];
    }
    int bn_[4], bk4[4];
    const float *b1p[4], *b2p[4];
#pragma unroll
    for (int p = 0; p < 4; p++) {
        int idx = tid + p * 256;
        bn_[p] = idx & 127; bk4[p] = (idx >> 7) * 4;
        b1p[p] = Wsd + (size_t)bk4[p] * H + (n0 + bn_[p]);
        b2p[p] = W2  + (size_t)bk4[p] * H + (n0 + bn_[p]);
    }

    f32x4 acc[4][4];
#pragma unroll
    for (int i = 0; i < 4; i++)
#pragma unroll
        for (int j = 0; j < 4; j++) acc[i][j] = (f32x4){0.f, 0.f, 0.f, 0.f};

    bf16x8 w1[2], w2[2];
    float4 vb1[4], vb2[4];
#pragma unroll
    for (int p = 0; p < 2; p++) { w1[p] = *(const bf16x8*)a1p[p]; w2[p] = *(const bf16x8*)a2p[p]; }
#pragma unroll
    for (int p = 0; p < 4; p++) {
        const float* b1 = b1p[p]; const float* b2 = b2p[p];
        vb1[p] = make_float4(b1[0], b1[(size_t)H], b1[2*(size_t)H], b1[3*(size_t)H]);
        vb2[p] = make_float4(b2[0], b2[(size_t)H], b2[2*(size_t)H], b2[3*(size_t)H]);
    }

    const int nK = I / BK;
    const int kh = (lane >> 4) * 8;
    for (int kt = 0; kt < nK; kt++) {
        __syncthreads();
#pragma unroll
        for (int p = 0; p < 2; p++) {
            *(bf16x8*)&A1[a_row[p]][a_c8[p]] = w1[p];
            *(bf16x8*)&A2[a_row[p]][a_c8[p]] = w2[p];
        }
#pragma unroll
        for (int p = 0; p < 4; p++) {
            lds_st8(&B1[bn_[p]][bk4[p]], vb1[p].x, vb1[p].y, vb1[p].z, vb1[p].w);
            lds_st8(&B2[bn_[p]][bk4[p]], vb2[p].x, vb2[p].y, vb2[p].z, vb2[p].w);
        }
        __syncthreads();
        if (kt + 1 < nK) {
            const int k0 = (kt + 1) * BK;
#pragma unroll
            for (int p = 0; p < 2; p++) {
                w1[p] = *(const bf16x8*)(a1p[p] + k0);
                w2[p] = *(const bf16x8*)(a2p[p] + k0);
            }
#pragma unroll
            for (int p = 0; p < 4; p++) {
                const float* b1 = b1p[p] + (size_t)k0 * H;
                const float* b2 = b2p[p] + (size_t)k0 * H;
                vb1[p] = make_float4(b1[0], b1[(size_t)H], b1[2*(size_t)H], b1[3*(size_t)H]);
                vb2[p] = make_float4(b2[0], b2[(size_t)H], b2[2*(size_t)H], b2[3*(size_t)H]);
            }
        }
        bf16x8 a1f[4], a2f[4], b1f[4], b2f[4];
#pragma unroll
        for (int q = 0; q < 4; q++) {
            a1f[q] = *(const bf16x8*)&A1[wr*64 + q*16 + (lane & 15)][kh];
            a2f[q] = *(const bf16x8*)&A2[wr*64 + q*16 + (lane & 15)][kh];
            b1f[q] = *(const bf16x8*)&B1[wc*64 + q*16 + (lane & 15)][kh];
            b2f[q] = *(const bf16x8*)&B2[wc*64 + q*16 + (lane & 15)][kh];
        }
#pragma unroll
        for (int mi = 0; mi < 4; mi++)
#pragma unroll
            for (int nj = 0; nj < 4; nj++) {
                acc[mi][nj] = __builtin_amdgcn_mfma_f32_16x16x32_bf16(a1f[mi], b1f[nj], acc[mi][nj], 0, 0, 0);
                acc[mi][nj] = __builtin_amdgcn_mfma_f32_16x16x32_bf16(a2f[mi], b2f[nj], acc[mi][nj], 0, 0, 0);
            }
    }

    const int rb = (lane >> 4) * 4, cb = lane & 15;
#pragma unroll
    for (int mi = 0; mi < 4; mi++)
#pragma unroll
        for (int nj = 0; nj < 4; nj++) {
            int col = n0 + wc*64 + nj*16 + cb;
#pragma unroll
            for (int j = 0; j < 4; j++) {
                int lr = wr*64 + mi*16 + rb + j;
                int tok = toks[lr];
                if (tok >= 0) out[(size_t)tok * H + col] = acc[mi][nj][j];
            }
        }
}

// ---------------- launcher ----------------

extern "C" void kernel_launch(void* const* d_in, const int* in_sizes, int n_in,
                              void* d_out, int out_size, void* d_ws, size_t ws_size,
                              hipStream_t stream)
{
    const float* x   = (const float*)d_in[0];
    const float* rw  = (const float*)d_in[1];
    const float* gup = (const float*)d_in[2];
    const float* dp  = (const float*)d_in[3];
    const float* sg  = (const float*)d_in[4];
    const float* su  = (const float*)d_in[5];
    const float* sd  = (const float*)d_in[6];

    const int H = 2048, I = 4096, E = 8;
    const int T = in_sizes[0] / H;            // 2048

    float* out        = (float*)d_out;
    float* scores_out = out + (size_t)T * H;  // router_scores [E, T]

    const int slotsCap = T + E * BM;          // 3072
    unsigned short* routedH = (unsigned short*)d_ws;                  // [slotsCap, I] bf16
    unsigned short* sharedH = routedH + (size_t)slotsCap * I;         // [T, I] bf16
    int*   list   = (int*)(sharedH + (size_t)T * I);                  // [slotsCap]
    int*   eidx   = list + slotsCap;                                  // [T]
    float* score  = (float*)(eidx + T);                               // [T]
    int*   counts = (int*)(score + T);                                // [E]
    int*   cursor = counts + E;                                       // [E]
    int*   offs   = cursor + E;                                       // [E]
    int*   ntile  = offs + E;                                         // [1]
    int*   tile_e = ntile + 1;                                        // [MAXT]
    int*   tile_m = tile_e + MAXT;                                    // [MAXT]

    const int maxTiles = T / BM + E;          // 24 (>= worst-case padded tile count)

    hipMemsetAsync(counts, 0, 2 * E * sizeof(int), stream);
    router_kernel<<<(T * E) / 256, 256, 0, stream>>>(x, rw, scores_out, eidx, score, counts, T, H, E);
    prefix_kernel<<<1, 1, 0, stream>>>(counts, offs, tile_e, tile_m, ntile, E);
    scatter_kernel<<<(T + 255) / 256, 256, 0, stream>>>(eidx, offs, cursor, list, T);
    shared_up<<<dim3(I / BN, T / BM), 256, 0, stream>>>(x, sg, su, sharedH, H, I);
    routed_up<<<dim3(I / BN, maxTiles), 256, 0, stream>>>(x, gup, counts, offs, list, score,
                                                          tile_e, tile_m, ntile, routedH, H, I);
    fused_down<<<dim3(H / BN, maxTiles), 256, 0, stream>>>(sharedH, routedH, sd, dp,
                                                           counts, offs, list,
                                                           tile_e, tile_m, ntile, out, I, H);
}